// Round 1
// baseline (529.459 us; speedup 1.0000x reference)
//
#include <hip/hip_runtime.h>

#define IN_F 128
#define OUT_F 128
#define KER 4
#define BM 64
#define BK 32

// ---------------- CSR build ----------------

__global__ void hist_kernel(const int* __restrict__ row, int E, int* __restrict__ counts) {
    int e = blockIdx.x * blockDim.x + threadIdx.x;
    if (e < E) atomicAdd(&counts[row[e]], 1);
}

// Single-block exclusive scan over counts[n] -> row_ptr[n+1], cursor[n] (= row_ptr[i])
__global__ void scan_kernel(const int* __restrict__ counts, int n,
                            int* __restrict__ row_ptr, int* __restrict__ cursor) {
    __shared__ int wsum[16];
    __shared__ int carry;
    const int tid = threadIdx.x;
    const int lane = tid & 63;
    const int wv = tid >> 6;
    if (tid == 0) { carry = 0; row_ptr[0] = 0; }
    __syncthreads();
    for (int base = 0; base < n; base += 1024) {
        const int i = base + tid;
        int v = (i < n) ? counts[i] : 0;
        int s = v;
        #pragma unroll
        for (int off = 1; off < 64; off <<= 1) {
            int t = __shfl_up(s, off, 64);
            if (lane >= off) s += t;
        }
        if (lane == 63) wsum[wv] = s;
        __syncthreads();
        if (wv == 0 && lane < 16) {
            int w = wsum[lane];
            #pragma unroll
            for (int off = 1; off < 16; off <<= 1) {
                int t = __shfl_up(w, off, 64);
                if (lane >= off) w += t;
            }
            wsum[lane] = w;
        }
        __syncthreads();
        const int c0 = carry;
        const int waveoff = (wv == 0) ? 0 : wsum[wv - 1];
        const int incl = c0 + waveoff + s;
        if (i < n) { row_ptr[i + 1] = incl; cursor[i] = incl - v; }
        __syncthreads();
        if (tid == 0) carry = c0 + wsum[15];
        __syncthreads();
    }
}

// Scatter edges into CSR order; compute the 4 Gaussian edge values once per edge.
__global__ void scatter_kernel(const int* __restrict__ row, const int* __restrict__ col, int E,
                               const float* __restrict__ x, const float* __restrict__ mu,
                               const float* __restrict__ sig,
                               int* __restrict__ cursor, int* __restrict__ col_sorted,
                               float4* __restrict__ val_sorted) {
    int e = blockIdx.x * blockDim.x + threadIdx.x;
    if (e >= E) return;
    int r = row[e], c = col[e];
    int pos = atomicAdd(&cursor[r], 1);
    col_sorted[pos] = c;
    const float* xr = x + (size_t)r * IN_F;
    const float* xc = x + (size_t)c * IN_F;
    float d0 = xr[0] - xc[0];
    float d1 = xr[1] - xc[1];
    float d2 = xr[2] - xc[2];
    float4 v;
    float* vv = &v.x;
    #pragma unroll
    for (int k = 0; k < 4; ++k) {
        float t0 = d0 - mu[0 * 4 + k];
        float t1 = d1 - mu[1 * 4 + k];
        float t2 = d2 - mu[2 * 4 + k];
        float s2 = t0 * t0 + t1 * t1 + t2 * t2;
        vv[k] = __expf(-0.5f * sig[k] * s2);
    }
    val_sorted[pos] = v;
}

// ---------------- Aggregation: agg[i][k*128+c] = sum_{e: row=i} v_k * x[col][c] ----------------

__global__ void __launch_bounds__(128) agg_kernel(
    const float* __restrict__ x, const int* __restrict__ row_ptr,
    const int* __restrict__ col_sorted, const float4* __restrict__ val_sorted,
    float* __restrict__ agg, int n) {
    const int i = blockIdx.x;
    const int c = threadIdx.x;
    const int start = row_ptr[i];
    const int end = row_ptr[i + 1];
    float a0 = 0.f, a1 = 0.f, a2 = 0.f, a3 = 0.f;
    #pragma unroll 2
    for (int j = start; j < end; ++j) {
        int col = col_sorted[j];
        float4 v = val_sorted[j];
        float xc = x[(size_t)col * IN_F + c];
        a0 += v.x * xc;
        a1 += v.y * xc;
        a2 += v.z * xc;
        a3 += v.w * xc;
    }
    size_t o = (size_t)i * (KER * IN_F);
    agg[o + 0 * 128 + c] = a0;
    agg[o + 1 * 128 + c] = a1;
    agg[o + 2 * 128 + c] = a2;
    agg[o + 3 * 128 + c] = a3;
}

// ---------------- Weight repack: W2[(k*128+c)*128 + f] = w[c][f][k] ----------------

__global__ void repack_kernel(const float* __restrict__ w, float* __restrict__ W2) {
    int idx = blockIdx.x * blockDim.x + threadIdx.x; // 512*128
    int f = idx & 127;
    int q = idx >> 7;
    int k = q >> 7;
    int c = q & 127;
    W2[idx] = w[c * (OUT_F * KER) + f * KER + k];
}

// ---------------- GEMM: out[n x 128] = agg[n x 512] @ W2[512 x 128] + bias ----------------

__global__ void __launch_bounds__(256) gemm_kernel(
    const float* __restrict__ agg, const float* __restrict__ W2,
    const float* __restrict__ bias, float* __restrict__ out, int n) {
    __shared__ float As[BM][BK + 1];
    __shared__ float Bs[BK][OUT_F];
    const int tid = threadIdx.x;
    const int tx = tid & 15;
    const int ty = tid >> 4;
    const int row0 = blockIdx.x * BM;

    float acc[4][8];
    #pragma unroll
    for (int r = 0; r < 4; ++r)
        #pragma unroll
        for (int j = 0; j < 8; ++j) acc[r][j] = 0.f;

    for (int kk = 0; kk < KER * IN_F; kk += BK) {
        #pragma unroll
        for (int it = 0; it < 2; ++it) {
            int fid = tid + it * 256;          // 0..511
            int r = fid >> 3;
            int c4 = (fid & 7) << 2;
            int grow = row0 + r;
            float4 val = make_float4(0.f, 0.f, 0.f, 0.f);
            if (grow < n)
                val = *reinterpret_cast<const float4*>(&agg[(size_t)grow * 512 + kk + c4]);
            As[r][c4 + 0] = val.x;
            As[r][c4 + 1] = val.y;
            As[r][c4 + 2] = val.z;
            As[r][c4 + 3] = val.w;
        }
        #pragma unroll
        for (int it = 0; it < 4; ++it) {
            int fid = tid + it * 256;          // 0..1023
            int r = fid >> 5;
            int c4 = (fid & 31) << 2;
            float4 val = *reinterpret_cast<const float4*>(&W2[(size_t)(kk + r) * 128 + c4]);
            *reinterpret_cast<float4*>(&Bs[r][c4]) = val;
        }
        __syncthreads();
        #pragma unroll
        for (int k = 0; k < BK; ++k) {
            float a[4], b[8];
            #pragma unroll
            for (int r = 0; r < 4; ++r) a[r] = As[ty * 4 + r][k];
            #pragma unroll
            for (int j = 0; j < 8; ++j) b[j] = Bs[k][tx * 8 + j];
            #pragma unroll
            for (int r = 0; r < 4; ++r)
                #pragma unroll
                for (int j = 0; j < 8; ++j)
                    acc[r][j] += a[r] * b[j];
        }
        __syncthreads();
    }

    #pragma unroll
    for (int r = 0; r < 4; ++r) {
        int grow = row0 + ty * 4 + r;
        if (grow < n) {
            #pragma unroll
            for (int j = 0; j < 8; ++j) {
                int f = tx * 8 + j;
                out[(size_t)grow * OUT_F + f] = acc[r][j] + bias[f];
            }
        }
    }
}

// ---------------- launch ----------------

extern "C" void kernel_launch(void* const* d_in, const int* in_sizes, int n_in,
                              void* d_out, int out_size, void* d_ws, size_t ws_size,
                              hipStream_t stream) {
    const float* x      = (const float*)d_in[0];
    const int*   edge   = (const int*)d_in[1];
    const float* weight = (const float*)d_in[2];
    const float* bias   = (const float*)d_in[3];
    const float* mu     = (const float*)d_in[4];
    const float* sig    = (const float*)d_in[5];
    float* out = (float*)d_out;

    const int n = in_sizes[0] / IN_F;
    const int E = in_sizes[1] / 2;
    const int* row = edge;
    const int* col = edge + E;

    char* ws = (char*)d_ws;
    size_t off = 0;
    auto alloc = [&](size_t bytes) {
        size_t o = off;
        off = (off + bytes + 15) & ~(size_t)15;
        return o;
    };
    float*  agg        = (float*)(ws + alloc((size_t)n * KER * IN_F * 4));
    float4* val_sorted = (float4*)(ws + alloc((size_t)E * 16));
    int*    col_sorted = (int*)(ws + alloc((size_t)E * 4));
    int*    row_ptr    = (int*)(ws + alloc(((size_t)n + 1) * 4));
    int*    cursor     = (int*)(ws + alloc((size_t)n * 4));
    int*    counts     = (int*)(ws + alloc((size_t)n * 4));
    float*  W2         = (float*)(ws + alloc((size_t)(KER * IN_F) * OUT_F * 4));
    if (off > ws_size) return;  // insufficient workspace: fail visibly rather than corrupt

    hipMemsetAsync(counts, 0, (size_t)n * 4, stream);
    hist_kernel<<<(E + 255) / 256, 256, 0, stream>>>(row, E, counts);
    scan_kernel<<<1, 1024, 0, stream>>>(counts, n, row_ptr, cursor);
    scatter_kernel<<<(E + 255) / 256, 256, 0, stream>>>(row, col, E, x, mu, sig,
                                                        cursor, col_sorted, val_sorted);
    agg_kernel<<<n, 128, 0, stream>>>(x, row_ptr, col_sorted, val_sorted, agg, n);
    repack_kernel<<<(512 * 128) / 256, 256, 0, stream>>>(weight, W2);
    gemm_kernel<<<(n + BM - 1) / BM, 256, 0, stream>>>(agg, W2, bias, out, n);
}

// Round 2
// 382.799 us; speedup vs baseline: 1.3831x; 1.3831x over previous
//
#include <hip/hip_runtime.h>

#define IN_F 128
#define OUT_F 128
#define KER 4

typedef unsigned int uint;
typedef unsigned short u16;
typedef __attribute__((ext_vector_type(8))) short bf16x8;
typedef __attribute__((ext_vector_type(4))) float f32x4;

__device__ __forceinline__ uint f2bf(float f) {
    uint u = __float_as_uint(f);
    u += 0x7fffu + ((u >> 16) & 1u);
    return u >> 16;
}

// ---------------- fused prep: x->bf16 + dom extract | W repack to frag layout | zero counts ----------------

__global__ void __launch_bounds__(256) prep_kernel(
    const float* __restrict__ x, const float* __restrict__ weight, int n,
    u16* __restrict__ xbf, float4* __restrict__ dom, u16* __restrict__ W2p,
    int* __restrict__ counts, int nB1, int nB2) {
    const int b = blockIdx.x;
    if (b < nB1) {
        int t = b * 256 + threadIdx.x;               // one thread = 4 floats
        if (t < n * 32) {
            float4 v = *reinterpret_cast<const float4*>(x + (size_t)t * 4);
            uint2 o;
            o.x = f2bf(v.x) | (f2bf(v.y) << 16);
            o.y = f2bf(v.z) | (f2bf(v.w) << 16);
            *reinterpret_cast<uint2*>(xbf + (size_t)t * 4) = o;
            if ((t & 31) == 0) dom[t >> 5] = make_float4(v.x, v.y, v.z, 0.f);
        }
    } else if (b < nB1 + nB2) {
        int t = (b - nB1) * 256 + threadIdx.x;       // 0..8191, one B-fragment-lane each
        if (t < 8192) {
            int lane = t & 63;
            int nfks = t >> 6;                        // (nf*16 + ks)
            int ks = nfks & 15, nf = nfks >> 4;
            int f = nf * 16 + (lane & 15);
            int kbase = ks * 32 + ((lane >> 4) << 3);
            uint pk[4];
            #pragma unroll
            for (int jj = 0; jj < 4; ++jj) {
                int k0 = kbase + jj * 2;
                int c0 = k0 & 127, q0 = k0 >> 7;
                int k1 = k0 + 1;
                int c1 = k1 & 127, q1 = k1 >> 7;
                uint lo = f2bf(weight[((size_t)c0 * OUT_F + f) * KER + q0]);
                uint hi = f2bf(weight[((size_t)c1 * OUT_F + f) * KER + q1]);
                pk[jj] = lo | (hi << 16);
            }
            *reinterpret_cast<uint4*>(W2p + (size_t)t * 8) =
                make_uint4(pk[0], pk[1], pk[2], pk[3]);
        }
    } else {
        int t = (b - nB1 - nB2) * 256 + threadIdx.x;
        if (t < n) counts[t] = 0;
    }
}

// ---------------- CSR build ----------------

__global__ void hist_kernel(const int* __restrict__ row, int E, int* __restrict__ counts) {
    int e = blockIdx.x * blockDim.x + threadIdx.x;
    if (e < E) atomicAdd(&counts[row[e]], 1);
}

__global__ void scanA_kernel(const int* __restrict__ counts, int n, int* __restrict__ bsum) {
    __shared__ int wsum[16];
    int i = blockIdx.x * 1024 + threadIdx.x;
    int lane = threadIdx.x & 63, wv = threadIdx.x >> 6;
    int v = (i < n) ? counts[i] : 0;
    #pragma unroll
    for (int off = 32; off > 0; off >>= 1) v += __shfl_down(v, off, 64);
    if (lane == 0) wsum[wv] = v;
    __syncthreads();
    if (threadIdx.x == 0) {
        int t = 0;
        #pragma unroll
        for (int q = 0; q < 16; ++q) t += wsum[q];
        bsum[blockIdx.x] = t;
    }
}

__global__ void scanB_kernel(const int* __restrict__ bsum, int nb, int* __restrict__ boff) {
    int lane = threadIdx.x;  // 64 threads, nb <= 64
    int v = (lane < nb) ? bsum[lane] : 0;
    int s = v;
    #pragma unroll
    for (int off = 1; off < 64; off <<= 1) {
        int t = __shfl_up(s, off, 64);
        if (lane >= off) s += t;
    }
    if (lane < nb) boff[lane] = s - v;
}

__global__ void scanC_kernel(const int* __restrict__ counts, int n, const int* __restrict__ boff,
                             int* __restrict__ row_ptr, int* __restrict__ cursor) {
    __shared__ int wsum[16];
    const int tid = threadIdx.x, lane = tid & 63, wv = tid >> 6;
    const int i = blockIdx.x * 1024 + tid;
    int v = (i < n) ? counts[i] : 0;
    int s = v;
    #pragma unroll
    for (int off = 1; off < 64; off <<= 1) {
        int t = __shfl_up(s, off, 64);
        if (lane >= off) s += t;
    }
    if (lane == 63) wsum[wv] = s;
    __syncthreads();
    if (wv == 0 && lane < 16) {
        int w = wsum[lane];
        #pragma unroll
        for (int off = 1; off < 16; off <<= 1) {
            int t = __shfl_up(w, off, 64);
            if (lane >= off) w += t;
        }
        wsum[lane] = w;
    }
    __syncthreads();
    int base = boff[blockIdx.x] + (wv ? wsum[wv - 1] : 0);
    int incl = base + s;
    if (i < n) { row_ptr[i + 1] = incl; cursor[i] = incl - v; }
    if (i == 0) row_ptr[0] = 0;
}

// Scatter edges into CSR order; 16B record = {4 bf16 gaussian values, col, pad}
__global__ void scatter_kernel(const int* __restrict__ row, const int* __restrict__ col, int E,
                               const float4* __restrict__ dom, const float* __restrict__ mu,
                               const float* __restrict__ sig,
                               int* __restrict__ cursor, int4* __restrict__ recs) {
    int e = blockIdx.x * blockDim.x + threadIdx.x;
    if (e >= E) return;
    int r = row[e], c = col[e];
    float4 dr = dom[r], dc = dom[c];
    float d0 = dr.x - dc.x, d1 = dr.y - dc.y, d2 = dr.z - dc.z;
    uint vb[4];
    #pragma unroll
    for (int k = 0; k < 4; ++k) {
        float t0 = d0 - mu[k];
        float t1 = d1 - mu[4 + k];
        float t2 = d2 - mu[8 + k];
        float s2 = t0 * t0 + t1 * t1 + t2 * t2;
        vb[k] = f2bf(__expf(-0.5f * sig[k] * s2));
    }
    int pos = atomicAdd(&cursor[r], 1);
    recs[pos] = make_int4((int)(vb[0] | (vb[1] << 16)), (int)(vb[2] | (vb[3] << 16)), c, 0);
}

// ---------------- Aggregation: one wave per row; agg_bf[i][k*128+c] ----------------

__global__ void __launch_bounds__(64) agg_kernel(
    const u16* __restrict__ xbf, const int* __restrict__ row_ptr,
    const int4* __restrict__ recs, u16* __restrict__ aggbf, int n) {
    const int i = blockIdx.x;
    const int l = threadIdx.x;
    int start = __builtin_amdgcn_readfirstlane(row_ptr[i]);
    int end   = __builtin_amdgcn_readfirstlane(row_ptr[i + 1]);
    float a00 = 0.f, a01 = 0.f, a10 = 0.f, a11 = 0.f;
    float a20 = 0.f, a21 = 0.f, a30 = 0.f, a31 = 0.f;
    for (int j = start; j < end; ++j) {
        int4 rec = recs[j];
        uint lo = (uint)rec.x, hi = (uint)rec.y;
        int c = rec.z;
        uint xp = *reinterpret_cast<const uint*>(xbf + ((size_t)c << 7) + (l << 1));
        float x0 = __uint_as_float(xp << 16);
        float x1 = __uint_as_float(xp & 0xffff0000u);
        float v0 = __uint_as_float(lo << 16);
        float v1 = __uint_as_float(lo & 0xffff0000u);
        float v2 = __uint_as_float(hi << 16);
        float v3 = __uint_as_float(hi & 0xffff0000u);
        a00 = fmaf(v0, x0, a00); a01 = fmaf(v0, x1, a01);
        a10 = fmaf(v1, x0, a10); a11 = fmaf(v1, x1, a11);
        a20 = fmaf(v2, x0, a20); a21 = fmaf(v2, x1, a21);
        a30 = fmaf(v3, x0, a30); a31 = fmaf(v3, x1, a31);
    }
    u16* o = aggbf + ((size_t)i << 9) + (l << 1);
    *reinterpret_cast<uint*>(o +   0) = f2bf(a00) | (f2bf(a01) << 16);
    *reinterpret_cast<uint*>(o + 128) = f2bf(a10) | (f2bf(a11) << 16);
    *reinterpret_cast<uint*>(o + 256) = f2bf(a20) | (f2bf(a21) << 16);
    *reinterpret_cast<uint*>(o + 384) = f2bf(a30) | (f2bf(a31) << 16);
}

// ---------------- GEMM: out[n x 128] = agg_bf[n x 512] @ W2 + bias, MFMA, no LDS ----------------

__global__ void __launch_bounds__(256) gemm_kernel(
    const u16* __restrict__ aggbf, const u16* __restrict__ W2p,
    const float* __restrict__ bias, float* __restrict__ out, int n) {
    const int w = threadIdx.x >> 6, l = threadIdx.x & 63;
    const int r0 = blockIdx.x * 128 + w * 32;
    int ra = r0 + (l & 15);
    int rb = ra + 16;
    if (ra > n - 1) ra = n - 1;
    if (rb > n - 1) rb = n - 1;
    const u16* pa = aggbf + ((size_t)ra << 9) + ((l >> 4) << 3);
    const u16* pb = aggbf + ((size_t)rb << 9) + ((l >> 4) << 3);
    const u16* wp = W2p + ((size_t)l << 3);

    f32x4 acc[2][8];
    #pragma unroll
    for (int m = 0; m < 2; ++m)
        #pragma unroll
        for (int nf = 0; nf < 8; ++nf)
            acc[m][nf] = (f32x4){0.f, 0.f, 0.f, 0.f};

    #pragma unroll 2
    for (int ks = 0; ks < 16; ++ks) {
        bf16x8 a0 = *reinterpret_cast<const bf16x8*>(pa + ks * 32);
        bf16x8 a1 = *reinterpret_cast<const bf16x8*>(pb + ks * 32);
        #pragma unroll
        for (int nf = 0; nf < 8; ++nf) {
            bf16x8 bfr = *reinterpret_cast<const bf16x8*>(wp + (((nf << 4) + ks) << 9));
            acc[0][nf] = __builtin_amdgcn_mfma_f32_16x16x32_bf16(a0, bfr, acc[0][nf], 0, 0, 0);
            acc[1][nf] = __builtin_amdgcn_mfma_f32_16x16x32_bf16(a1, bfr, acc[1][nf], 0, 0, 0);
        }
    }

    const int cq = l >> 4;     // row quadrant
    const int cr = l & 15;     // output feature within frag
    #pragma unroll
    for (int nf = 0; nf < 8; ++nf) {
        float bv = bias[(nf << 4) + cr];
        #pragma unroll
        for (int m = 0; m < 2; ++m) {
            #pragma unroll
            for (int rg = 0; rg < 4; ++rg) {
                int rowi = r0 + m * 16 + cq * 4 + rg;
                if (rowi < n)
                    out[(size_t)rowi * OUT_F + (nf << 4) + cr] = acc[m][nf][rg] + bv;
            }
        }
    }
}

// ---------------- launch ----------------

extern "C" void kernel_launch(void* const* d_in, const int* in_sizes, int n_in,
                              void* d_out, int out_size, void* d_ws, size_t ws_size,
                              hipStream_t stream) {
    const float* x      = (const float*)d_in[0];
    const int*   edge   = (const int*)d_in[1];
    const float* weight = (const float*)d_in[2];
    const float* bias   = (const float*)d_in[3];
    const float* mu     = (const float*)d_in[4];
    const float* sig    = (const float*)d_in[5];
    float* out = (float*)d_out;

    const int n = in_sizes[0] / IN_F;
    const int E = in_sizes[1] / 2;
    const int* row = edge;
    const int* col = edge + E;

    char* ws = (char*)d_ws;
    size_t off = 0;
    auto alloc = [&](size_t bytes) {
        size_t o = off;
        off = (off + bytes + 255) & ~(size_t)255;
        return o;
    };
    u16*    xbf     = (u16*)(ws + alloc((size_t)n * IN_F * 2));
    float4* dom     = (float4*)(ws + alloc((size_t)n * 16));
    int4*   recs    = (int4*)(ws + alloc((size_t)E * 16));
    u16*    aggbf   = (u16*)(ws + alloc((size_t)n * KER * IN_F * 2));
    u16*    W2p     = (u16*)(ws + alloc((size_t)KER * IN_F * OUT_F * 2));
    int*    counts  = (int*)(ws + alloc((size_t)n * 4));
    int*    row_ptr = (int*)(ws + alloc(((size_t)n + 1) * 4));
    int*    cursor  = (int*)(ws + alloc((size_t)n * 4));
    int*    bsum    = (int*)(ws + alloc(1024 * 4));
    int*    boff    = (int*)(ws + alloc(1024 * 4));
    if (off > ws_size) return;  // insufficient workspace: fail visibly rather than corrupt

    const int nB1 = (n * 32 + 255) / 256;
    const int nB2 = 32;
    const int nB3 = (n + 255) / 256;
    prep_kernel<<<nB1 + nB2 + nB3, 256, 0, stream>>>(x, weight, n, xbf, dom, W2p,
                                                     counts, nB1, nB2);
    hist_kernel<<<(E + 255) / 256, 256, 0, stream>>>(row, E, counts);
    const int nb = (n + 1023) / 1024;
    scanA_kernel<<<nb, 1024, 0, stream>>>(counts, n, bsum);
    scanB_kernel<<<1, 64, 0, stream>>>(bsum, nb, boff);
    scanC_kernel<<<nb, 1024, 0, stream>>>(counts, n, boff, row_ptr, cursor);
    scatter_kernel<<<(E + 255) / 256, 256, 0, stream>>>(row, col, E, dom, mu, sig,
                                                        cursor, recs);
    agg_kernel<<<n, 64, 0, stream>>>(xbf, row_ptr, recs, aggbf, n);
    gemm_kernel<<<(n + 127) / 128, 256, 0, stream>>>(aggbf, W2p, bias, out, n);
}